// Round 1
// baseline (1511.078 us; speedup 1.0000x reference)
//
#include <hip/hip_runtime.h>
#include <math.h>

// Problem constants
#define NDIM 768
#define NHEADS 12
#define HD 64
#define SEQ 1024
#define BATCH 8
#define MROWS (BATCH * SEQ)          // 8192
#define SQRT_DIM 27.712812921102035f // sqrt(768) = 1/SCALE_PARAM_INIT

// ---------------------------------------------------------------------------
// C[M,N] = A[M,K] @ B[N,K]^T  (torch Linear), fp32, row-major.
// 64x64 block tile, BK=16, 256 threads, 4x4 microtile.
// LDS staged K-major (As[kk][row]) so compute reads are b128.
// ---------------------------------------------------------------------------
__global__ __launch_bounds__(256) void gemm_nt(const float* __restrict__ A,
                                               const float* __restrict__ B,
                                               float* __restrict__ C,
                                               int M, int N, int K) {
    __shared__ float As[16][68];
    __shared__ float Bs[16][68];
    const int t = threadIdx.x;
    const int tx = t & 15;          // col group 0..15
    const int ty = t >> 4;          // row group 0..15
    const int bm = blockIdx.y * 64;
    const int bn = blockIdx.x * 64;
    const int lrow = t >> 2;        // 0..63
    const int lc4 = (t & 3) * 4;    // 0,4,8,12

    float acc[4][4] = {};

    for (int k0 = 0; k0 < K; k0 += 16) {
        float4 av = *(const float4*)(A + (size_t)(bm + lrow) * K + k0 + lc4);
        float4 bv = *(const float4*)(B + (size_t)(bn + lrow) * K + k0 + lc4);
        // transpose into LDS: As[kk][row] (2-way bank alias on write = free)
        As[lc4 + 0][lrow] = av.x; As[lc4 + 1][lrow] = av.y;
        As[lc4 + 2][lrow] = av.z; As[lc4 + 3][lrow] = av.w;
        Bs[lc4 + 0][lrow] = bv.x; Bs[lc4 + 1][lrow] = bv.y;
        Bs[lc4 + 2][lrow] = bv.z; Bs[lc4 + 3][lrow] = bv.w;
        __syncthreads();
#pragma unroll
        for (int kk = 0; kk < 16; ++kk) {
            float4 a = *(const float4*)&As[kk][4 * ty];  // broadcast read
            float4 b = *(const float4*)&Bs[kk][4 * tx];  // 2-way = free
            float ar[4] = {a.x, a.y, a.z, a.w};
            float br[4] = {b.x, b.y, b.z, b.w};
#pragma unroll
            for (int i = 0; i < 4; ++i)
#pragma unroll
                for (int j = 0; j < 4; ++j) acc[i][j] += ar[i] * br[j];
        }
        __syncthreads();
    }
#pragma unroll
    for (int i = 0; i < 4; ++i) {
        float4 o = make_float4(acc[i][0], acc[i][1], acc[i][2], acc[i][3]);
        *(float4*)(C + (size_t)(bm + 4 * ty + i) * N + bn + 4 * tx) = o;
    }
}

// ---------------------------------------------------------------------------
// Cosine-norm + scale, in place. X is [G,64] with G = B*N*H; h = g % 12.
// One wave per 64-vector.
// ---------------------------------------------------------------------------
__global__ __launch_bounds__(256) void normscale(float* __restrict__ X,
                                                 const float* __restrict__ s_qk,
                                                 int G) {
    const int gid = (int)((blockIdx.x * 256 + threadIdx.x) >> 6);
    const int lane = threadIdx.x & 63;
    if (gid >= G) return;
    const size_t idx = (size_t)gid * 64 + lane;
    float v = X[idx];
    float ss = v * v;
#pragma unroll
    for (int off = 32; off >= 1; off >>= 1) ss += __shfl_xor(ss, off, 64);
    float nrm = fmaxf(sqrtf(ss), 1e-6f);
    int h = gid % NHEADS;
    float se = s_qk[h * HD + lane] * SQRT_DIM;
    X[idx] = v / nrm * se;
}

// ---------------------------------------------------------------------------
// Flash-style attention. Q,K,V are [B,N,H,64] fp32 (already cos-normed and
// scaled). Output O is [B,N,768] (head-major concat). One block handles one
// (b, h, 64-query tile); streams over 16 key tiles of 64.
// Logit scale = sqrt(64) = 8 (applied to S).
// Microtile: thread (tx,ty) owns rows 4*ty..+3.
//   S-phase columns: tx + 16*j  (keeps K-tile LDS reads 2-way/free)
//   PV-phase columns: 4*tx + c  (mapping decoupled via P round-trip in LDS)
// ---------------------------------------------------------------------------
__global__ __launch_bounds__(256) void attn_fwd(const float* __restrict__ Q,
                                                const float* __restrict__ K,
                                                const float* __restrict__ V,
                                                float* __restrict__ O) {
    __shared__ float Qs[64][68];
    __shared__ float KPs[64][68];   // K tile, reused to hold P
    __shared__ float Vs[64][68];

    const int t = threadIdx.x;
    const int tx = t & 15;
    const int ty = t >> 4;
    const int b = blockIdx.z;
    const int h = blockIdx.y;
    const int q0 = blockIdx.x * 64;
    const int lrow = t >> 2;       // 0..63
    const int lc = (t & 3) * 4;    // 0,4,8,12

    // Stage Q tile (64 rows x 64 dims)
    {
        const float* qb = Q + (((size_t)(b * SEQ + q0 + lrow)) * NHEADS + h) * HD;
#pragma unroll
        for (int u = 0; u < 4; ++u)
            *(float4*)&Qs[lrow][u * 16 + lc] = *(const float4*)(qb + u * 16 + lc);
    }

    float m_i[4], l_i[4], o_acc[4][4];
#pragma unroll
    for (int i = 0; i < 4; ++i) {
        m_i[i] = -INFINITY;
        l_i[i] = 0.f;
#pragma unroll
        for (int j = 0; j < 4; ++j) o_acc[i][j] = 0.f;
    }

    for (int j0 = 0; j0 < SEQ; j0 += 64) {
        __syncthreads();  // prev iter done reading Vs/KPs (also covers Q stage)
        {
            const float* kb = K + (((size_t)(b * SEQ + j0 + lrow)) * NHEADS + h) * HD;
            const float* vb = V + (((size_t)(b * SEQ + j0 + lrow)) * NHEADS + h) * HD;
#pragma unroll
            for (int u = 0; u < 4; ++u) {
                *(float4*)&KPs[lrow][u * 16 + lc] = *(const float4*)(kb + u * 16 + lc);
                *(float4*)&Vs[lrow][u * 16 + lc]  = *(const float4*)(vb + u * 16 + lc);
            }
        }
        __syncthreads();

        // S = (Q K^T) * 8, rows 4ty+i, cols tx+16j
        float s[4][4] = {};
#pragma unroll
        for (int d = 0; d < HD; d += 4) {
            float4 qv[4], kv[4];
#pragma unroll
            for (int i = 0; i < 4; ++i) qv[i] = *(const float4*)&Qs[4 * ty + i][d];
#pragma unroll
            for (int j = 0; j < 4; ++j) kv[j] = *(const float4*)&KPs[tx + 16 * j][d];
#pragma unroll
            for (int i = 0; i < 4; ++i)
#pragma unroll
                for (int j = 0; j < 4; ++j)
                    s[i][j] += qv[i].x * kv[j].x + qv[i].y * kv[j].y +
                               qv[i].z * kv[j].z + qv[i].w * kv[j].w;
        }
        __syncthreads();  // everyone done reading K tile; safe to overwrite as P

        // Online softmax per row; per-row state replicated across the 16
        // lanes of each row group (identical by construction).
#pragma unroll
        for (int i = 0; i < 4; ++i) {
            float rmax = -INFINITY;
#pragma unroll
            for (int j = 0; j < 4; ++j) {
                s[i][j] *= 8.f;
                rmax = fmaxf(rmax, s[i][j]);
            }
#pragma unroll
            for (int off = 1; off < 16; off <<= 1)
                rmax = fmaxf(rmax, __shfl_xor(rmax, off, 64));
            float mnew = fmaxf(m_i[i], rmax);
            float alpha = __expf(m_i[i] - mnew);
            float rsum = 0.f;
#pragma unroll
            for (int j = 0; j < 4; ++j) {
                float p = __expf(s[i][j] - mnew);
                s[i][j] = p;
                rsum += p;
            }
#pragma unroll
            for (int off = 1; off < 16; off <<= 1)
                rsum += __shfl_xor(rsum, off, 64);
            l_i[i] = l_i[i] * alpha + rsum;
            m_i[i] = mnew;
#pragma unroll
            for (int j = 0; j < 4; ++j) o_acc[i][j] *= alpha;
            // scatter P into LDS (column mapping tx+16j)
#pragma unroll
            for (int j = 0; j < 4; ++j) KPs[4 * ty + i][tx + 16 * j] = s[i][j];
        }
        __syncthreads();  // P visible to all

        // O += P @ V  (rows 4ty+i, cols 4tx+c)
#pragma unroll
        for (int j = 0; j < 64; j += 4) {
            float4 pv[4], vv[4];
#pragma unroll
            for (int i = 0; i < 4; ++i) pv[i] = *(const float4*)&KPs[4 * ty + i][j];
#pragma unroll
            for (int jj = 0; jj < 4; ++jj) vv[jj] = *(const float4*)&Vs[j + jj][4 * tx];
#pragma unroll
            for (int i = 0; i < 4; ++i) {
                float pr[4] = {pv[i].x, pv[i].y, pv[i].z, pv[i].w};
#pragma unroll
                for (int c = 0; c < 4; ++c) {
                    float vcol[4] = {((const float*)&vv[0])[c], ((const float*)&vv[1])[c],
                                     ((const float*)&vv[2])[c], ((const float*)&vv[3])[c]};
                    o_acc[i][c] += pr[0] * vcol[0] + pr[1] * vcol[1] +
                                   pr[2] * vcol[2] + pr[3] * vcol[3];
                }
            }
        }
    }

    // Final normalize by l and write [B,N,768]
#pragma unroll
    for (int i = 0; i < 4; ++i) {
        float invl = 1.0f / l_i[i];
        float4 o = make_float4(o_acc[i][0] * invl, o_acc[i][1] * invl,
                               o_acc[i][2] * invl, o_acc[i][3] * invl);
        *(float4*)(O + ((size_t)(b * SEQ + q0 + 4 * ty + i)) * NDIM + h * HD + 4 * tx) = o;
    }
}

// ---------------------------------------------------------------------------
extern "C" void kernel_launch(void* const* d_in, const int* in_sizes, int n_in,
                              void* d_out, int out_size, void* d_ws, size_t ws_size,
                              hipStream_t stream) {
    const float* x    = (const float*)d_in[0];
    const float* Wq   = (const float*)d_in[1];
    const float* Wk   = (const float*)d_in[2];
    const float* Wv   = (const float*)d_in[3];
    const float* Wo   = (const float*)d_in[4];
    const float* s_qk = (const float*)d_in[5];
    float* out = (float*)d_out;

    const size_t tensor_elems = (size_t)MROWS * NDIM;  // 6,291,456
    float* q  = (float*)d_ws;
    float* k  = q + tensor_elems;
    float* v  = k + tensor_elems;
    float* ao = v + tensor_elems;

    dim3 gemm_grid(NDIM / 64, MROWS / 64);  // (12, 128)

    gemm_nt<<<gemm_grid, 256, 0, stream>>>(x, Wq, q, MROWS, NDIM, NDIM);
    gemm_nt<<<gemm_grid, 256, 0, stream>>>(x, Wk, k, MROWS, NDIM, NDIM);
    gemm_nt<<<gemm_grid, 256, 0, stream>>>(x, Wv, v, MROWS, NDIM, NDIM);

    const int G = MROWS * NHEADS;  // 98304 groups of 64
    normscale<<<G / 4, 256, 0, stream>>>(q, s_qk, G);
    normscale<<<G / 4, 256, 0, stream>>>(k, s_qk, G);

    attn_fwd<<<dim3(SEQ / 64, NHEADS, BATCH), 256, 0, stream>>>(q, k, v, ao);

    gemm_nt<<<gemm_grid, 256, 0, stream>>>(ao, Wo, out, MROWS, NDIM, NDIM);
}

// Round 2
// 318.557 us; speedup vs baseline: 4.7435x; 4.7435x over previous
//
#include <hip/hip_runtime.h>
#include <hip/hip_bf16.h>
#include <math.h>

#define NDIM 768
#define NHEADS 12
#define HD 64
#define SEQ 1024
#define BATCH 8
#define MROWS (BATCH * SEQ)          // 8192
#define SQRT_DIM 27.712812921102035f // 1/SCALE_PARAM_INIT
#define LOG2E 1.4426950408889634f

typedef unsigned short u16;
typedef __attribute__((ext_vector_type(8))) short short8; // 8 bf16 = 4 VGPRs
typedef __attribute__((ext_vector_type(4))) float f32x4;

#define MFMA16(a, b, c) __builtin_amdgcn_mfma_f32_16x16x32_bf16(a, b, c, 0, 0, 0)

__device__ inline u16 f2bf(float f) {
    __hip_bfloat16 h = __float2bfloat16(f);
    return *reinterpret_cast<u16*>(&h);
}

// async 16B global->LDS. lds dest must be wave-uniform base; HW adds lane*16.
__device__ inline void gl2lds16(const void* g, void* l) {
    __builtin_amdgcn_global_load_lds((const __attribute__((address_space(1))) void*)g,
                                     (__attribute__((address_space(3))) void*)l, 16, 0, 0);
}

// ---------------------------------------------------------------------------
// fp32 -> bf16 cast, 4 elems/thread. n % 1024 == 0 for all uses.
// ---------------------------------------------------------------------------
__global__ __launch_bounds__(256) void castk(const float* __restrict__ s,
                                             u16* __restrict__ d, int n) {
    int i = (blockIdx.x * 256 + threadIdx.x) * 4;
    if (i >= n) return;
    float4 v = *(const float4*)(s + i);
    d[i] = f2bf(v.x); d[i + 1] = f2bf(v.y); d[i + 2] = f2bf(v.z); d[i + 3] = f2bf(v.w);
}

// ---------------------------------------------------------------------------
// bf16 MFMA GEMM: C[M,N] = A[M,768] @ B[N,768]^T, fp32 accum.
// 128x128 tile, BK=32, 256 threads (4 waves, 2x2 of 64x64), m97 structure.
// EPI 0: fp32 row-major C.  EPI 1: bf16 write transposed into Vt[b,h,d,tok].
// ---------------------------------------------------------------------------
template <int EPI>
__global__ __launch_bounds__(256) void gemm_bf16(const u16* __restrict__ A,
                                                 const u16* __restrict__ B,
                                                 void* __restrict__ C, int N) {
    constexpr int K = NDIM;
    __shared__ __align__(16) u16 As[128 * 32];
    __shared__ __align__(16) u16 Bs[128 * 32];
    const int t = threadIdx.x;
    const int wave = t >> 6, lane = t & 63;
    const int quad = lane >> 4, l16 = lane & 15;
    const int wx = (wave & 1) * 64, wy = (wave >> 1) * 64;
    const int bm = blockIdx.y * 128, bn = blockIdx.x * 128;

    f32x4 acc[4][4];
#pragma unroll
    for (int i = 0; i < 4; ++i)
#pragma unroll
        for (int j = 0; j < 4; ++j) acc[i][j] = (f32x4){0.f, 0.f, 0.f, 0.f};

    for (int k0 = 0; k0 < K; k0 += 32) {
        __syncthreads();
#pragma unroll
        for (int it = 0; it < 2; ++it) {
            const int cb = it * 256 + wave * 64;       // wave-uniform chunk base
            const int c = cb + lane;                   // this lane's chunk
            const int row = c >> 2, kc = c & 3;        // 4 x 16B chunks per 32-elem row
            gl2lds16(A + (size_t)(bm + row) * K + k0 + kc * 8, (char*)As + cb * 16);
            gl2lds16(B + (size_t)(bn + row) * K + k0 + kc * 8, (char*)Bs + cb * 16);
        }
        asm volatile("s_waitcnt vmcnt(0)" ::: "memory");
        __syncthreads();

        short8 af[4], bf[4];
#pragma unroll
        for (int i = 0; i < 4; ++i)
            af[i] = *(const short8*)&As[(wy + i * 16 + l16) * 32 + quad * 8];
#pragma unroll
        for (int j = 0; j < 4; ++j)
            bf[j] = *(const short8*)&Bs[(wx + j * 16 + l16) * 32 + quad * 8];
#pragma unroll
        for (int i = 0; i < 4; ++i)
#pragma unroll
            for (int j = 0; j < 4; ++j) acc[i][j] = MFMA16(af[i], bf[j], acc[i][j]);
    }

#pragma unroll
    for (int i = 0; i < 4; ++i)
#pragma unroll
        for (int j = 0; j < 4; ++j)
#pragma unroll
            for (int r = 0; r < 4; ++r) {
                const int row = bm + wy + i * 16 + quad * 4 + r;
                const int col = bn + wx + j * 16 + l16;
                if (EPI == 0) {
                    ((float*)C)[(size_t)row * N + col] = acc[i][j][r];
                } else {
                    // row = token, col = h*64+d ; Vt[(b*12+h)*64+d][tok within 1024]
                    const int b = row >> 10, n = row & 1023;
                    const int h = col >> 6, dd = col & 63;
                    ((u16*)C)[(((size_t)(b * NHEADS + h) * HD + dd) << 10) + n] =
                        f2bf(acc[i][j][r]);
                }
            }
}

// ---------------------------------------------------------------------------
// Cosine-norm + scale + repack to bf16 head-major [b,h,tok,64].
// qk is [8192][1536] fp32 (q heads then k heads). One wave per vector.
// q gets an extra 8*log2(e) factor (logit scale + exp2 domain).
// ---------------------------------------------------------------------------
__global__ __launch_bounds__(256) void norm_qk(const float* __restrict__ qk,
                                               const float* __restrict__ s_qk,
                                               u16* __restrict__ Qh,
                                               u16* __restrict__ Kh) {
    const int wid = (blockIdx.x * 256 + threadIdx.x) >> 6;
    const int lane = threadIdx.x & 63;
    const int tok = wid / 24, r = wid % 24;
    const int sel = r / 12, h = r % 12; // sel 0 = q, 1 = k
    float v = qk[(size_t)tok * 1536 + r * 64 + lane];
    float ss = v * v;
#pragma unroll
    for (int o = 32; o >= 1; o >>= 1) ss += __shfl_xor(ss, o, 64);
    float nrm = fmaxf(sqrtf(ss), 1e-6f);
    float scale = s_qk[h * HD + lane] * (SQRT_DIM / nrm);
    if (sel == 0) scale *= 8.f * LOG2E;
    u16* dst = sel ? Kh : Qh;
    dst[((size_t)((tok >> 10) * NHEADS + h) * SEQ + (tok & 1023)) * HD + lane] =
        f2bf(v * scale);
}

// ---------------------------------------------------------------------------
// MFMA flash attention. Qh/Kh: [b,h,tok,64] bf16 (q pre-scaled by 8*log2e),
// Vt: [b,h,d,tok] bf16. Out AO: [tok, 768] bf16 (token-major, head concat).
// Block = (b, h, 64-query tile); wave w owns queries w*16..w*16+15.
// ---------------------------------------------------------------------------
__global__ __launch_bounds__(256) void attn_mfma(const u16* __restrict__ Qh,
                                                 const u16* __restrict__ Kh,
                                                 const u16* __restrict__ Vt,
                                                 u16* __restrict__ AO) {
    __shared__ __align__(16) u16 Ks[64 * 64];      // [tok][d]
    __shared__ __align__(16) u16 Vs[64 * 64];      // [d][tok]
    __shared__ __align__(16) u16 Ps[4][16][80];    // per-wave P strip, padded

    const int t = threadIdx.x;
    const int wave = t >> 6, lane = t & 63;
    const int quad = lane >> 4, l16 = lane & 15;
    const int b = blockIdx.z, h = blockIdx.y, q0 = blockIdx.x * 64;
    const int bh = b * NHEADS + h;
    const u16* Kb = Kh + (size_t)bh * SEQ * HD;
    const u16* Vb = Vt + (size_t)bh * HD * SEQ;

    // Q strip -> registers (A-operand layout: m=l16, k=quad*8+j [+32])
    short8 qf[2];
    {
        const u16* qr = Qh + ((size_t)bh * SEQ + q0 + wave * 16 + l16) * HD + quad * 8;
        qf[0] = *(const short8*)qr;
        qf[1] = *(const short8*)(qr + 32);
    }

    float m_i[4], l_i[4];
    f32x4 o_acc[4];
#pragma unroll
    for (int r = 0; r < 4; ++r) { m_i[r] = -INFINITY; l_i[r] = 0.f; }
#pragma unroll
    for (int nt = 0; nt < 4; ++nt) o_acc[nt] = (f32x4){0.f, 0.f, 0.f, 0.f};

    for (int j0 = 0; j0 < SEQ; j0 += 64) {
        __syncthreads();
        // stage K tile (globally contiguous 8KB) and V^T tile
        {
            const char* kg = (const char*)(Kb + (size_t)j0 * HD);
            const char* vg = (const char*)(Vb + j0);
#pragma unroll
            for (int it = 0; it < 2; ++it) {
                const int cb = it * 256 + wave * 64;
                const int c = cb + lane;
                gl2lds16(kg + c * 16, (char*)Ks + cb * 16);
                const int d = c >> 3, p = c & 7; // Vt row d, 16B part p
                gl2lds16(vg + (size_t)d * (SEQ * 2) + p * 16, (char*)Vs + cb * 16);
            }
        }
        asm volatile("s_waitcnt vmcnt(0)" ::: "memory");
        __syncthreads();

        // S strip: 16 queries x 64 keys (logits already in log2 domain)
        f32x4 s[4];
#pragma unroll
        for (int nt = 0; nt < 4; ++nt) {
            short8 k0f = *(const short8*)&Ks[(nt * 16 + l16) * 64 + quad * 8];
            short8 k1f = *(const short8*)&Ks[(nt * 16 + l16) * 64 + 32 + quad * 8];
            f32x4 z = (f32x4){0.f, 0.f, 0.f, 0.f};
            z = MFMA16(qf[0], k0f, z);
            s[nt] = MFMA16(qf[1], k1f, z);
        }

        // online softmax; lane owns rows quad*4+r (replicated over 16 lanes/quad)
#pragma unroll
        for (int r = 0; r < 4; ++r) {
            float mx = fmaxf(fmaxf(s[0][r], s[1][r]), fmaxf(s[2][r], s[3][r]));
            mx = fmaxf(mx, __shfl_xor(mx, 1, 64));
            mx = fmaxf(mx, __shfl_xor(mx, 2, 64));
            mx = fmaxf(mx, __shfl_xor(mx, 4, 64));
            mx = fmaxf(mx, __shfl_xor(mx, 8, 64));
            float mnew = fmaxf(m_i[r], mx);
            float alpha = exp2f(m_i[r] - mnew);
            m_i[r] = mnew;
            float rs = 0.f;
#pragma unroll
            for (int nt = 0; nt < 4; ++nt) {
                float p = exp2f(s[nt][r] - mnew);
                rs += p;
                Ps[wave][quad * 4 + r][nt * 16 + l16] = f2bf(p);
            }
            rs += __shfl_xor(rs, 1, 64);
            rs += __shfl_xor(rs, 2, 64);
            rs += __shfl_xor(rs, 4, 64);
            rs += __shfl_xor(rs, 8, 64);
            l_i[r] = l_i[r] * alpha + rs;
#pragma unroll
            for (int nt = 0; nt < 4; ++nt) o_acc[nt][r] *= alpha;
        }

        // PV: own-wave P strip only -> no barrier needed (compiler waits lgkm)
        short8 pf0 = *(const short8*)&Ps[wave][l16][quad * 8];
        short8 pf1 = *(const short8*)&Ps[wave][l16][32 + quad * 8];
#pragma unroll
        for (int nt = 0; nt < 4; ++nt) {
            short8 v0 = *(const short8*)&Vs[(nt * 16 + l16) * 64 + quad * 8];
            short8 v1 = *(const short8*)&Vs[(nt * 16 + l16) * 64 + 32 + quad * 8];
            o_acc[nt] = MFMA16(pf0, v0, o_acc[nt]);
            o_acc[nt] = MFMA16(pf1, v1, o_acc[nt]);
        }
    }

    float invl[4];
#pragma unroll
    for (int r = 0; r < 4; ++r) invl[r] = 1.f / l_i[r];
    u16* ob = AO + (size_t)(b * SEQ + q0 + wave * 16) * NDIM + h * HD;
#pragma unroll
    for (int nt = 0; nt < 4; ++nt)
#pragma unroll
        for (int r = 0; r < 4; ++r)
            ob[(quad * 4 + r) * NDIM + nt * 16 + l16] = f2bf(o_acc[nt][r] * invl[r]);
}

// ---------------------------------------------------------------------------
extern "C" void kernel_launch(void* const* d_in, const int* in_sizes, int n_in,
                              void* d_out, int out_size, void* d_ws, size_t ws_size,
                              hipStream_t stream) {
    const float* x    = (const float*)d_in[0];
    const float* Wq   = (const float*)d_in[1];
    const float* Wk   = (const float*)d_in[2];
    const float* Wv   = (const float*)d_in[3];
    const float* Wo   = (const float*)d_in[4];
    const float* s_qk = (const float*)d_in[5];
    float* out = (float*)d_out;

    // workspace layout (89.3 MB, with liveness-based aliasing):
    char* w = (char*)d_ws;
    size_t off = 0;
    float* qk = (float*)(w + off);                 // [8192][1536] fp32, 50.3 MB
    u16* ao = (u16*)(w + off);                     // alias: ao after qk is dead
    off += (size_t)MROWS * 1536 * 4;
    u16* Qh = (u16*)(w + off);                     // [b,h,tok,64] bf16 12.6 MB
    u16* xb = Qh;                                  // alias: xb dead before Qh written
    off += (size_t)MROWS * NDIM * 2;
    u16* Kh = (u16*)(w + off);                     // 12.6 MB
    u16* Wqkv = Kh;                                // alias: [2304][768] bf16 3.5 MB
    off += (size_t)MROWS * NDIM * 2;
    u16* Vt = (u16*)(w + off);                     // [b,h,d,tok] bf16 12.6 MB
    off += (size_t)MROWS * NDIM * 2;
    u16* Wob = (u16*)(w + off);                    // [768][768] bf16 1.2 MB

    const int WE = NDIM * NDIM; // 589824
    castk<<<(MROWS * NDIM) / 1024, 256, 0, stream>>>(x, xb, MROWS * NDIM);
    castk<<<WE / 1024, 256, 0, stream>>>(Wq, Wqkv, WE);
    castk<<<WE / 1024, 256, 0, stream>>>(Wk, Wqkv + WE, WE);
    castk<<<WE / 1024, 256, 0, stream>>>(Wv, Wqkv + 2 * WE, WE);
    castk<<<WE / 1024, 256, 0, stream>>>(Wo, Wob, WE);

    // QK projection: N=1536 fp32 out; V projection: N=768, bf16 transposed out
    gemm_bf16<0><<<dim3(1536 / 128, MROWS / 128), 256, 0, stream>>>(xb, Wqkv, qk, 1536);
    gemm_bf16<1><<<dim3(NDIM / 128, MROWS / 128), 256, 0, stream>>>(xb, Wqkv + 2 * WE,
                                                                    (void*)Vt, NDIM);
    norm_qk<<<(MROWS * NHEADS * 2) / 4, 256, 0, stream>>>(qk, s_qk, Qh, Kh);

    attn_mfma<<<dim3(SEQ / 64, NHEADS, BATCH), 256, 0, stream>>>(Qh, Kh, Vt, ao);

    gemm_bf16<0><<<dim3(NDIM / 128, MROWS / 128), 256, 0, stream>>>(ao, Wob, out, NDIM);
}

// Round 3
// 267.770 us; speedup vs baseline: 5.6432x; 1.1897x over previous
//
#include <hip/hip_runtime.h>
#include <hip/hip_bf16.h>
#include <math.h>

#define NDIM 768
#define NHEADS 12
#define HD 64
#define SEQ 1024
#define BATCH 8
#define MROWS (BATCH * SEQ)          // 8192
#define SQRT_DIM 27.712812921102035f // 1/SCALE_PARAM_INIT
#define LOG2E 1.4426950408889634f

typedef unsigned short u16;
typedef __attribute__((ext_vector_type(8))) short short8; // 8 bf16 = 4 VGPRs
typedef __attribute__((ext_vector_type(4))) float f32x4;

#define MFMA16(a, b, c) __builtin_amdgcn_mfma_f32_16x16x32_bf16(a, b, c, 0, 0, 0)

__device__ inline u16 f2bf(float f) {
    __hip_bfloat16 h = __float2bfloat16(f);
    return *reinterpret_cast<u16*>(&h);
}

// async 16B global->LDS. LDS dest is wave-uniform base; HW adds lane*16.
__device__ inline void gl2lds16(const void* g, void* l) {
    __builtin_amdgcn_global_load_lds((const __attribute__((address_space(1))) void*)g,
                                     (__attribute__((address_space(3))) void*)l, 16, 0, 0);
}

// ---------------------------------------------------------------------------
// One fused cast kernel: x (6144 blocks) + Wq/Wk/Wv -> Wqkv, Wo -> Wob.
// 1024 elems per block.
// ---------------------------------------------------------------------------
__global__ __launch_bounds__(256) void castall(const float* __restrict__ x,
                                               const float* __restrict__ Wq,
                                               const float* __restrict__ Wk,
                                               const float* __restrict__ Wv,
                                               const float* __restrict__ Wo,
                                               u16* __restrict__ xb,
                                               u16* __restrict__ Wqkv,
                                               u16* __restrict__ Wob) {
    const int WB = (NDIM * NDIM) / 1024; // 576 blocks per weight
    int blk = blockIdx.x;
    const float* s;
    u16* d;
    int base;
    if (blk < 6144) {
        s = x; d = xb; base = blk * 1024;
    } else {
        int wsel = (blk - 6144) / WB, r = (blk - 6144) % WB;
        base = r * 1024;
        if (wsel == 0)      { s = Wq; d = Wqkv; }
        else if (wsel == 1) { s = Wk; d = Wqkv + NDIM * NDIM; }
        else if (wsel == 2) { s = Wv; d = Wqkv + 2 * NDIM * NDIM; }
        else                { s = Wo; d = Wob; }
    }
    int i = base + threadIdx.x * 4;
    float4 v = *(const float4*)(s + i);
    d[i] = f2bf(v.x); d[i + 1] = f2bf(v.y); d[i + 2] = f2bf(v.z); d[i + 3] = f2bf(v.w);
}

// ---------------------------------------------------------------------------
// bf16 MFMA GEMM: C = A[M,768] @ B[N,768]^T, fp32 accum. 128x128 tile, BK=32,
// 4 waves (2x2 of 64x64). LDS layout is chunk-transposed: slot = kc*128+row
// (kc = 16B chunk within the 32-elem K-slab) so fragment ds_read_b128 bank
// group = l16%8 -> 2-way alias = free.
// EPI 0: fp32 row-major C[.][N].
// EPI 1: bf16 transposed into Vt[b,h,d,tok].
// EPI 2: cosine-norm per (row, head) + s_eff scale + bf16 write to
//        Qh/Kh [b,h,tok,64]; q also gets 8*log2(e) (logit scale, exp2 domain).
// ---------------------------------------------------------------------------
template <int EPI>
__global__ __launch_bounds__(256) void gemm_bf16(const u16* __restrict__ A,
                                                 const u16* __restrict__ B,
                                                 void* __restrict__ C, int N,
                                                 const float* __restrict__ s_qk,
                                                 u16* __restrict__ Qdst,
                                                 u16* __restrict__ Kdst) {
    constexpr int K = NDIM;
    __shared__ __align__(16) u16 As[512 * 8]; // 512 slots x 16B
    __shared__ __align__(16) u16 Bs[512 * 8];
    const int t = threadIdx.x;
    const int wave = t >> 6, lane = t & 63;
    const int quad = lane >> 4, l16 = lane & 15;
    const int wx = (wave & 1) * 64, wy = (wave >> 1) * 64;
    const int bm = blockIdx.y * 128, bn = blockIdx.x * 128;

    f32x4 acc[4][4];
#pragma unroll
    for (int i = 0; i < 4; ++i)
#pragma unroll
        for (int j = 0; j < 4; ++j) acc[i][j] = (f32x4){0.f, 0.f, 0.f, 0.f};

    for (int k0 = 0; k0 < K; k0 += 32) {
        __syncthreads();
#pragma unroll
        for (int it = 0; it < 2; ++it) {
            const int cb = it * 256 + wave * 64; // slot base (64-aligned)
            const int kc = cb >> 7;              // 0..3, uniform per 64-slot span
            const int row = (cb & 127) + lane;
            gl2lds16(A + (size_t)(bm + row) * K + k0 + kc * 8, (char*)As + cb * 16);
            gl2lds16(B + (size_t)(bn + row) * K + k0 + kc * 8, (char*)Bs + cb * 16);
        }
        asm volatile("s_waitcnt vmcnt(0)" ::: "memory");
        __syncthreads();

        short8 af[4], bf[4];
#pragma unroll
        for (int i = 0; i < 4; ++i)
            af[i] = *(const short8*)&As[(quad * 128 + wy + i * 16 + l16) * 8];
#pragma unroll
        for (int j = 0; j < 4; ++j)
            bf[j] = *(const short8*)&Bs[(quad * 128 + wx + j * 16 + l16) * 8];
#pragma unroll
        for (int i = 0; i < 4; ++i)
#pragma unroll
            for (int j = 0; j < 4; ++j) acc[i][j] = MFMA16(af[i], bf[j], acc[i][j]);
    }

    if constexpr (EPI == 0) {
#pragma unroll
        for (int i = 0; i < 4; ++i)
#pragma unroll
            for (int j = 0; j < 4; ++j)
#pragma unroll
                for (int r = 0; r < 4; ++r) {
                    const int row = bm + wy + i * 16 + quad * 4 + r;
                    const int col = bn + wx + j * 16 + l16;
                    ((float*)C)[(size_t)row * N + col] = acc[i][j][r];
                }
    } else if constexpr (EPI == 1) {
#pragma unroll
        for (int i = 0; i < 4; ++i)
#pragma unroll
            for (int j = 0; j < 4; ++j)
#pragma unroll
                for (int r = 0; r < 4; ++r) {
                    const int row = bm + wy + i * 16 + quad * 4 + r; // token
                    const int col = bn + wx + j * 16 + l16;          // h*64+d
                    const int b = row >> 10, n = row & 1023;
                    const int h = col >> 6, dd = col & 63;
                    ((u16*)C)[(((size_t)(b * NHEADS + h) * HD + dd) << 10) + n] =
                        f2bf(acc[i][j][r]);
                }
    } else {
        // EPI == 2: wave's 64 cols = one head of q (cols<768) or k
        const int cg = (bn + wx) >> 6; // 0..23
        const bool isq = cg < NHEADS;
        const int h = isq ? cg : cg - NHEADS;
        u16* dst = isq ? Qdst : Kdst;
        const float ex = isq ? 8.f * LOG2E : 1.f;
        float sq[4];
#pragma unroll
        for (int j = 0; j < 4; ++j)
            sq[j] = s_qk[h * HD + j * 16 + l16] * SQRT_DIM * ex;
#pragma unroll
        for (int i = 0; i < 4; ++i)
#pragma unroll
            for (int r = 0; r < 4; ++r) {
                float ss = 0.f;
#pragma unroll
                for (int j = 0; j < 4; ++j) ss += acc[i][j][r] * acc[i][j][r];
                ss += __shfl_xor(ss, 1, 64);
                ss += __shfl_xor(ss, 2, 64);
                ss += __shfl_xor(ss, 4, 64);
                ss += __shfl_xor(ss, 8, 64);
                float inv = 1.f / fmaxf(sqrtf(ss), 1e-6f);
                const int row = bm + wy + i * 16 + quad * 4 + r;
                const int b = row >> 10, tok = row & 1023;
                u16* o = dst + ((size_t)(b * NHEADS + h) * SEQ + tok) * HD;
#pragma unroll
                for (int j = 0; j < 4; ++j)
                    o[j * 16 + l16] = f2bf(acc[i][j][r] * sq[j] * inv);
            }
    }
}

// ---------------------------------------------------------------------------
// MFMA flash attention, no-max softmax (logits bounded by cosine norm).
// Qh/Kh: [b,h,tok,64] bf16 (q pre-scaled by 8*log2e), Vt: [b,h,d,tok] bf16.
// K/V LDS: chunk-transposed slot = kc*64 + row (kc = 16B chunk) -> fragment
// reads are 2-way bank aliases (free). Out AO: [tok,768] bf16.
// ---------------------------------------------------------------------------
__global__ __launch_bounds__(256) void attn_mfma(const u16* __restrict__ Qh,
                                                 const u16* __restrict__ Kh,
                                                 const u16* __restrict__ Vt,
                                                 u16* __restrict__ AO) {
    __shared__ __align__(16) u16 Ks[512 * 8];   // slot = kc*64 + tok
    __shared__ __align__(16) u16 Vs[512 * 8];   // slot = kc*64 + d  (kc = key chunk)
    __shared__ __align__(16) u16 Ps[4][16][72]; // pad 72: reads 2-way = free

    const int t = threadIdx.x;
    const int wave = t >> 6, lane = t & 63;
    const int quad = lane >> 4, l16 = lane & 15;
    const int b = blockIdx.z, h = blockIdx.y, q0 = blockIdx.x * 64;
    const int bh = b * NHEADS + h;
    const u16* Kb = Kh + (size_t)bh * SEQ * HD;
    const u16* Vb = Vt + (size_t)bh * HD * SEQ;

    // Q strip -> A-operand regs (m=l16, k=quad*8+j / +32)
    short8 qf[2];
    {
        const u16* qr = Qh + ((size_t)bh * SEQ + q0 + wave * 16 + l16) * HD + quad * 8;
        qf[0] = *(const short8*)qr;
        qf[1] = *(const short8*)(qr + 32);
    }

    float lp[4] = {0.f, 0.f, 0.f, 0.f};
    f32x4 o_acc[4];
#pragma unroll
    for (int nt = 0; nt < 4; ++nt) o_acc[nt] = (f32x4){0.f, 0.f, 0.f, 0.f};

    for (int j0 = 0; j0 < SEQ; j0 += 64) {
        __syncthreads();
#pragma unroll
        for (int it = 0; it < 2; ++it) {
            const int cb = it * 256 + wave * 64;
            const int kc = cb >> 6; // 0..7, uniform per 64-slot span
            gl2lds16(Kb + (size_t)(j0 + lane) * HD + kc * 8, (char*)Ks + cb * 16);
            gl2lds16(Vb + (size_t)lane * SEQ + j0 + kc * 8, (char*)Vs + cb * 16);
        }
        asm volatile("s_waitcnt vmcnt(0)" ::: "memory");
        __syncthreads();

        // S strip: 16 queries x 64 keys (log2-domain logits)
        f32x4 s[4];
#pragma unroll
        for (int nt = 0; nt < 4; ++nt) {
            short8 k0f = *(const short8*)&Ks[(quad * 64 + nt * 16 + l16) * 8];
            short8 k1f = *(const short8*)&Ks[((quad + 4) * 64 + nt * 16 + l16) * 8];
            f32x4 z = (f32x4){0.f, 0.f, 0.f, 0.f};
            z = MFMA16(qf[0], k0f, z);
            s[nt] = MFMA16(qf[1], k1f, z);
        }

        // no-max softmax: P = exp2(s); defer l reduction to the end
#pragma unroll
        for (int r = 0; r < 4; ++r) {
            float p0 = exp2f(s[0][r]), p1 = exp2f(s[1][r]);
            float p2 = exp2f(s[2][r]), p3 = exp2f(s[3][r]);
            lp[r] += (p0 + p1) + (p2 + p3);
            Ps[wave][quad * 4 + r][0 * 16 + l16] = f2bf(p0);
            Ps[wave][quad * 4 + r][1 * 16 + l16] = f2bf(p1);
            Ps[wave][quad * 4 + r][2 * 16 + l16] = f2bf(p2);
            Ps[wave][quad * 4 + r][3 * 16 + l16] = f2bf(p3);
        }

        // PV: own-wave P strip (compiler inserts lgkmcnt wait)
        short8 pf0 = *(const short8*)&Ps[wave][l16][quad * 8];
        short8 pf1 = *(const short8*)&Ps[wave][l16][32 + quad * 8];
#pragma unroll
        for (int nt = 0; nt < 4; ++nt) {
            short8 v0 = *(const short8*)&Vs[(quad * 64 + nt * 16 + l16) * 8];
            short8 v1 = *(const short8*)&Vs[((quad + 4) * 64 + nt * 16 + l16) * 8];
            o_acc[nt] = MFMA16(pf0, v0, o_acc[nt]);
            o_acc[nt] = MFMA16(pf1, v1, o_acc[nt]);
        }
    }

    float invl[4];
#pragma unroll
    for (int r = 0; r < 4; ++r) {
        float l = lp[r];
        l += __shfl_xor(l, 1, 64);
        l += __shfl_xor(l, 2, 64);
        l += __shfl_xor(l, 4, 64);
        l += __shfl_xor(l, 8, 64);
        invl[r] = 1.f / l;
    }
    u16* ob = AO + (size_t)(b * SEQ + q0 + wave * 16) * NDIM + h * HD;
#pragma unroll
    for (int nt = 0; nt < 4; ++nt)
#pragma unroll
        for (int r = 0; r < 4; ++r)
            ob[(quad * 4 + r) * NDIM + nt * 16 + l16] = f2bf(o_acc[nt][r] * invl[r]);
}

// ---------------------------------------------------------------------------
extern "C" void kernel_launch(void* const* d_in, const int* in_sizes, int n_in,
                              void* d_out, int out_size, void* d_ws, size_t ws_size,
                              hipStream_t stream) {
    const float* x    = (const float*)d_in[0];
    const float* Wq   = (const float*)d_in[1];
    const float* Wk   = (const float*)d_in[2];
    const float* Wv   = (const float*)d_in[3];
    const float* Wo   = (const float*)d_in[4];
    const float* s_qk = (const float*)d_in[5];
    float* out = (float*)d_out;

    // workspace: 67.6 MB, no aliasing
    char* w = (char*)d_ws;
    const size_t TE = (size_t)MROWS * NDIM; // 6,291,456
    u16* xb   = (u16*)w;                    w += TE * 2;
    u16* Wqkv = (u16*)w;                    w += (size_t)3 * NDIM * NDIM * 2;
    u16* Wob  = (u16*)w;                    w += (size_t)NDIM * NDIM * 2;
    u16* Qh   = (u16*)w;                    w += TE * 2;
    u16* Kh   = (u16*)w;                    w += TE * 2;
    u16* Vt   = (u16*)w;                    w += TE * 2;
    u16* ao   = (u16*)w;

    castall<<<6144 + 4 * 576, 256, 0, stream>>>(x, Wq, Wk, Wv, Wo, xb, Wqkv, Wob);

    // QK projection + fused cosine-norm epilogue -> Qh, Kh
    gemm_bf16<2><<<dim3(1536 / 128, MROWS / 128), 256, 0, stream>>>(
        xb, Wqkv, nullptr, 1536, s_qk, Qh, Kh);
    // V projection, transposed bf16 epilogue -> Vt
    gemm_bf16<1><<<dim3(NDIM / 128, MROWS / 128), 256, 0, stream>>>(
        xb, Wqkv + 2 * NDIM * NDIM, (void*)Vt, NDIM, nullptr, nullptr, nullptr);

    attn_mfma<<<dim3(SEQ / 64, NHEADS, BATCH), 256, 0, stream>>>(Qh, Kh, Vt, ao);

    gemm_bf16<0><<<dim3(NDIM / 128, MROWS / 128), 256, 0, stream>>>(
        ao, Wob, out, NDIM, nullptr, nullptr, nullptr);
}